// Round 1
// baseline (224.775 us; speedup 1.0000x reference)
//
#include <hip/hip_runtime.h>

#define N_PTS 4096
#define D_EMB 64
#define TILE  128

// ---------------------------------------------------------------------------
// Row squared-norms: one wave per row, coalesced, shuffle reduce.
// ---------------------------------------------------------------------------
__global__ void row_norms_kernel(const float* __restrict__ mapping,
                                 float* __restrict__ nrm) {
  const int row = blockIdx.x;
  const int l = threadIdx.x;          // 0..63
  float v = mapping[row * D_EMB + l];
  float s = v * v;
  #pragma unroll
  for (int off = 32; off > 0; off >>= 1) s += __shfl_down(s, off);
  if (l == 0) nrm[row] = s;
}

// ---------------------------------------------------------------------------
// Fused pairwise-distance + distortion partial sums.
// Block: 256 threads -> 128x128 output tile, 8x8 per thread (rows/cols
// interleaved stride-8: thread owns rows ra+8m, cols cb+8n).
// LDS: two 128x64 f32 tiles (exactly 64 KB), XOR-swizzled at float4
// granularity (col4' = c4 ^ (row&7)) so k-chunk b128 reads are
// bank-conflict-free without padding.
// ---------------------------------------------------------------------------
__global__ __launch_bounds__(256, 2) void distortion_main(
    const float* __restrict__ mapping, const float* __restrict__ Dm,
    const float* __restrict__ nrm, double* __restrict__ acc) {
  __shared__ float As[TILE][D_EMB];
  __shared__ float Bs[TILE][D_EMB];

  const int t = threadIdx.x;
  const int i0 = blockIdx.y * TILE;
  const int j0 = blockIdx.x * TILE;

  // ---- stage tiles: fully coalesced float4 global loads, swizzled LDS write
  {
    const float4* gA = (const float4*)(mapping + (size_t)i0 * D_EMB);
    const float4* gB = (const float4*)(mapping + (size_t)j0 * D_EMB);
    #pragma unroll
    for (int i = 0; i < 8; ++i) {
      const int f = i * 256 + t;     // float4 index within the 128x64 tile
      const int r = f >> 4;          // row 0..127
      const int c4 = f & 15;         // float4-col 0..15
      const int sc4 = c4 ^ (r & 7);  // swizzle (bijective within row)
      *(float4*)&As[r][sc4 * 4] = gA[f];
      *(float4*)&Bs[r][sc4 * 4] = gB[f];
    }
  }
  __syncthreads();

  const int w = t >> 6, l = t & 63;
  const int li = l >> 3, lj = l & 7;
  const int wi = w >> 1, wj = w & 1;
  const int ra = wi * 64 + li;  // thread rows: ra + 8m   (r & 7 == li)
  const int cb = wj * 64 + lj;  // thread cols: cb + 8n   (r & 7 == lj)

  float acc_t[8][8];
  #pragma unroll
  for (int m = 0; m < 8; ++m)
    #pragma unroll
    for (int n = 0; n < 8; ++n) acc_t[m][n] = 0.f;

  for (int kc = 0; kc < 16; ++kc) {   // 4 k-values per chunk
    float4 a[8], b[8];
    #pragma unroll
    for (int m = 0; m < 8; ++m)
      a[m] = *(const float4*)&As[ra + 8 * m][(kc ^ li) * 4];
    #pragma unroll
    for (int n = 0; n < 8; ++n)
      b[n] = *(const float4*)&Bs[cb + 8 * n][(kc ^ lj) * 4];
    #pragma unroll
    for (int m = 0; m < 8; ++m)
      #pragma unroll
      for (int n = 0; n < 8; ++n) {
        acc_t[m][n] = fmaf(a[m].x, b[n].x, acc_t[m][n]);
        acc_t[m][n] = fmaf(a[m].y, b[n].y, acc_t[m][n]);
        acc_t[m][n] = fmaf(a[m].z, b[n].z, acc_t[m][n]);
        acc_t[m][n] = fmaf(a[m].w, b[n].w, acc_t[m][n]);
      }
  }

  // ---- epilogue: distances + distortion partial sums
  float rnA[8], rnB[8];
  #pragma unroll
  for (int m = 0; m < 8; ++m) rnA[m] = nrm[i0 + ra + 8 * m];
  #pragma unroll
  for (int n = 0; n < 8; ++n) rnB[n] = nrm[j0 + cb + 8 * n];

  float s1 = 0.f, s2 = 0.f, s3 = 0.f, s4 = 0.f;
  #pragma unroll
  for (int m = 0; m < 8; ++m) {
    const int gr = i0 + ra + 8 * m;
    const float* __restrict__ Drow = Dm + (size_t)gr * N_PTS;
    #pragma unroll
    for (int n = 0; n < 8; ++n) {
      const int gc = j0 + cb + 8 * n;
      const float Dv = Drow[gc];
      const float dot = acc_t[m][n];
      float sq = rnA[m] + rnB[n] - 2.f * dot;
      float dd = (sq > 0.f) ? __builtin_amdgcn_sqrtf(sq) : 0.f;
      const bool diag = (gr == gc);
      if (diag) dd = 0.f;                       // exact: ||x-x|| = 0
      const float denom = Dv + (diag ? 1.f : 0.f) + 1e-8f;
      const float rd = __builtin_amdgcn_rcpf(denom);
      const float av = dd * rd;                 // a = d/denom
      const float bv = Dv * rd;                 // b = D/denom
      s1 += av;                                 // sum a
      s2 = fmaf(av, av, s2);                    // sum a^2
      s3 = fmaf(av, bv, s3);                    // sum a*b
      s4 = fmaf(bv, bv, s4);                    // sum b^2
    }
  }

  // ---- reduction: wave shuffle, then f64 atomics (4 per wave)
  #pragma unroll
  for (int off = 32; off > 0; off >>= 1) {
    s1 += __shfl_down(s1, off);
    s2 += __shfl_down(s2, off);
    s3 += __shfl_down(s3, off);
    s4 += __shfl_down(s4, off);
  }
  if (l == 0) {
    atomicAdd(&acc[0], (double)s1);
    atomicAdd(&acc[1], (double)s2);
    atomicAdd(&acc[2], (double)s3);
    atomicAdd(&acc[3], (double)s4);
  }
}

// ---------------------------------------------------------------------------
// Final scalar: sum(dist) = s^2*S2 - 2 s S3 + S4, s = S1/S2.
// ---------------------------------------------------------------------------
__global__ void distortion_final(const double* __restrict__ acc,
                                 float* __restrict__ out) {
  const double S1 = acc[0], S2 = acc[1], S3 = acc[2], S4 = acc[3];
  const double s = S1 / S2;
  const double r = (s * s * S2 - 2.0 * s * S3 + S4) /
                   ((double)N_PTS * (double)N_PTS - (double)N_PTS);
  out[0] = (float)r;
}

extern "C" void kernel_launch(void* const* d_in, const int* in_sizes, int n_in,
                              void* d_out, int out_size, void* d_ws, size_t ws_size,
                              hipStream_t stream) {
  const float* mapping = (const float*)d_in[0];
  const float* Dm = (const float*)d_in[1];
  float* out = (float*)d_out;
  double* acc = (double*)d_ws;                    // 4 doubles
  float* nrm = (float*)((char*)d_ws + 64);        // 4096 f32 row norms

  hipMemsetAsync(d_ws, 0, 64, stream);            // zero accumulators each call
  row_norms_kernel<<<dim3(N_PTS), dim3(64), 0, stream>>>(mapping, nrm);
  distortion_main<<<dim3(N_PTS / TILE, N_PTS / TILE), dim3(256), 0, stream>>>(
      mapping, Dm, nrm, acc);
  distortion_final<<<1, 1, 0, stream>>>(acc, out);
}